// Round 7
// baseline (1295.167 us; speedup 1.0000x reference)
//
#include <hip/hip_runtime.h>

// GRUModel: 2-layer GRU (H=64), B=4096, T=512, fp32 in/out — MFMA round 7.
//
// R7: fully wave-local GRU — ZERO barriers, zero inter-wave traffic.
// 256 blocks x 4 waves; each wave owns 4 batch rows and computes the whole
// cell (all 64 units, both layers) via per-wave-private LDS h-planes.
// In-order per-wave DS pipe makes the C->A LDS round-trip safe without any
// __syncthreads; 1024 waves = 1 wave/SIMD on all 256 CUs, free-running.
//
// Row placement trick: real row j sits at MFMA tile row m=4j (other A rows
// stay zero forever). C-layout D[m=4q+r][n] then puts row q's real gates in
// reg 0 of EVERY lane: lane (q,n) owns (row q, units 16v+n) -> 8 gate cells
// per wave per step, no spread shuffles, all 64 lanes useful in gate math.
//
// Numerics (unchanged from R4, absmax 4.9e-4): split-fp16 2-product
// D=(Ah+Al)@Bh with Ah=fp16(h), Al=fp16(h-Ah); weights single fp16; h-state
// fp32 in registers. All 72 weight B-frags (288 VGPR) register-resident.
//
// Frag layouts (m89/m120-verified):
//   A: lane holds A[m=lane&15][k=(lane>>4)*8+j], j=0..7
//   B: lane holds B[k=(lane>>4)*8+j][n=lane&15]
//   C/D: lane holds D[m=(lane>>4)*4+reg][n=lane&15]

typedef _Float16 half8 __attribute__((ext_vector_type(8)));
typedef float    v4f   __attribute__((ext_vector_type(4)));

#define T_LEN 512
#define KS 72   // fp16 row stride of h planes: 144B = 36 words ≡ 4 (mod 32)
                // -> full-wave b128 A-reads land exactly 8/bank (minimum)

static __device__ __forceinline__ float sigm(float x) {
    return 1.0f / (1.0f + __expf(-x));
}
static __device__ __forceinline__ float tanh_fast(float x) {
    return 2.0f / (1.0f + __expf(-2.0f * x)) - 1.0f;
}
static __device__ __forceinline__ v4f mfma16(half8 a, half8 b, v4f c) {
    return __builtin_amdgcn_mfma_f32_16x16x32_f16(a, b, c, 0, 0, 0);
}
static __device__ __forceinline__ half8 ld8(const _Float16* p) {
    return *(const half8*)p;
}

__global__ __launch_bounds__(256, 1)
void gru_wave(const float* __restrict__ x,
              const float* __restrict__ w_ih0, const float* __restrict__ w_hh0,
              const float* __restrict__ b_ih0, const float* __restrict__ b_hh0,
              const float* __restrict__ w_ih1, const float* __restrict__ w_hh1,
              const float* __restrict__ b_ih1, const float* __restrict__ b_hh1,
              const float* __restrict__ fc_w,  const float* __restrict__ fc_b,
              float* __restrict__ out)
{
    // per-wave-private planes: [wave][h0hi, h0lo, h1hi, h1lo][16*KS]
    __shared__ __align__(16) _Float16 planes[4][4][16 * KS];

    const int tid  = threadIdx.x;
    const int wv   = tid >> 6;
    const int lane = tid & 63;
    const int n    = lane & 15;
    const int q    = lane >> 4;

    _Float16* h0hi = planes[wv][0];
    _Float16* h0lo = planes[wv][1];
    _Float16* h1hi = planes[wv][2];
    _Float16* h1lo = planes[wv][3];

    // zero own planes (garbage A-rows m!=4j must stay 0 forever)
    {
        _Float16* b = planes[wv][0];
        for (int i = lane; i < 4 * 16 * KS; i += 64) b[i] = (_Float16)0;
    }

    // ---- loop-invariant weight B-fragments (single fp16), all in VGPRs ----
    half8 B0[3][4][2];   // [gate][v][chunk]  W_hh0, K=64
    half8 B1[3][4][4];   // [gate][v][chunk]  c<2: W_ih1 (A=h0new), c>=2: W_hh1 (A=h1)
    #pragma unroll
    for (int g = 0; g < 3; g++) {
        #pragma unroll
        for (int v = 0; v < 4; v++) {
            const int row = g * 64 + 16 * v + n;
            #pragma unroll
            for (int c = 0; c < 2; c++) {
                const float* p = w_hh0 + row * 64 + 32 * c + 8 * q;
                #pragma unroll
                for (int j = 0; j < 8; j++) B0[g][v][c][j] = (_Float16)p[j];
            }
            #pragma unroll
            for (int c = 0; c < 4; c++) {
                const float* M = (c < 2) ? w_ih1 : w_hh1;
                const float* p = M + row * 64 + 32 * (c & 1) + 8 * q;
                #pragma unroll
                for (int j = 0; j < 8; j++) B1[g][v][c][j] = (_Float16)p[j];
            }
        }
    }

    // per-(lane,v) gate constants (unit u = 16v+n)
    float wir[4], wiz[4], win[4], br0[4], bz0[4], bin0[4], bhn0[4];
    float br1[4], bz1[4], bin1[4], bhn1[4];
    #pragma unroll
    for (int v = 0; v < 4; v++) {
        const int u = 16 * v + n;
        wir[v] = w_ih0[u]; wiz[v] = w_ih0[64 + u]; win[v] = w_ih0[128 + u];
        br0[v] = b_ih0[u] + b_hh0[u];
        bz0[v] = b_ih0[64 + u] + b_hh0[64 + u];
        bin0[v] = b_ih0[128 + u]; bhn0[v] = b_hh0[128 + u];
        br1[v] = b_ih1[u] + b_hh1[u];
        bz1[v] = b_ih1[64 + u] + b_hh1[64 + u];
        bin1[v] = b_ih1[128 + u]; bhn1[v] = b_hh1[128 + u];
    }

    float h0p[4] = {0.f, 0.f, 0.f, 0.f};   // h0[row q][16v+n], fp32 authoritative
    float h1p[4] = {0.f, 0.f, 0.f, 0.f};

    const int rowbase = (blockIdx.x * 4 + wv) * 4;
    const float* xr = x + (size_t)(rowbase + q) * T_LEN;   // per-lane row = q
    float xv = xr[0];

    const int ab = n * KS + 8 * q;          // A-frag read base (fp16 elems)
    const int wb = (4 * q) * KS + n;        // write base: row q at m=4q, +16v

    #pragma unroll 1
    for (int t = 0; t < T_LEN; t++) {
        const int tn = (t + 1 < T_LEN) ? t + 1 : t;
        const float xn_ = xr[tn];           // prefetch next x (hidden by step)

        // ======== layer 0: G0 = (h0hi+h0lo) @ W_hh0^T ========
        const half8 a0h[2] = { ld8(h0hi + ab), ld8(h0hi + ab + 32) };
        const half8 a0l[2] = { ld8(h0lo + ab), ld8(h0lo + ab + 32) };

        v4f aR[4], aZ[4], aN[4];
        #pragma unroll
        for (int v = 0; v < 4; v++)
            #pragma unroll
            for (int r = 0; r < 4; r++) { aR[v][r] = 0.f; aZ[v][r] = 0.f; aN[v][r] = 0.f; }

        #pragma unroll
        for (int v = 0; v < 4; v++) {       // 12 chains of depth 4
            aR[v] = mfma16(a0h[0], B0[0][v][0], aR[v]);
            aZ[v] = mfma16(a0h[0], B0[1][v][0], aZ[v]);
            aN[v] = mfma16(a0h[0], B0[2][v][0], aN[v]);
            aR[v] = mfma16(a0h[1], B0[0][v][1], aR[v]);
            aZ[v] = mfma16(a0h[1], B0[1][v][1], aZ[v]);
            aN[v] = mfma16(a0h[1], B0[2][v][1], aN[v]);
            aR[v] = mfma16(a0l[0], B0[0][v][0], aR[v]);
            aZ[v] = mfma16(a0l[0], B0[1][v][0], aZ[v]);
            aN[v] = mfma16(a0l[0], B0[2][v][0], aN[v]);
            aR[v] = mfma16(a0l[1], B0[0][v][1], aR[v]);
            aZ[v] = mfma16(a0l[1], B0[1][v][1], aZ[v]);
            aN[v] = mfma16(a0l[1], B0[2][v][1], aN[v]);
        }

        // gates: reg 0 of each acc = row q (real); regs 1..3 are garbage rows
        _Float16 w0hi[4], w0lo[4];
        #pragma unroll
        for (int v = 0; v < 4; v++) {
            const float rg = sigm(aR[v][0] + fmaf(xv, wir[v], br0[v]));
            const float zg = sigm(aZ[v][0] + fmaf(xv, wiz[v], bz0[v]));
            const float ng = tanh_fast(fmaf(xv, win[v], bin0[v])
                                       + rg * (aN[v][0] + bhn0[v]));
            const float h = ng + zg * (h0p[v] - ng);
            h0p[v] = h;
            w0hi[v] = (_Float16)h;
            w0lo[v] = (_Float16)(h - (float)w0hi[v]);
        }
        #pragma unroll
        for (int v = 0; v < 4; v++) {       // full-wave writes, row m=4q
            h0hi[wb + 16 * v] = w0hi[v];
            h0lo[wb + 16 * v] = w0lo[v];
        }

        // ======== layer 1: G1 = [h0new | h1] @ [W_ih1 ; W_hh1]^T ========
        // in-order per-wave DS pipe orders these reads after the writes above
        const half8 g0h[2] = { ld8(h0hi + ab), ld8(h0hi + ab + 32) };
        const half8 g0l[2] = { ld8(h0lo + ab), ld8(h0lo + ab + 32) };
        const half8 g1h[2] = { ld8(h1hi + ab), ld8(h1hi + ab + 32) };
        const half8 g1l[2] = { ld8(h1lo + ab), ld8(h1lo + ab + 32) };

        v4f cR[4], cZ[4], cNi[4], cNh[4];
        #pragma unroll
        for (int v = 0; v < 4; v++)
            #pragma unroll
            for (int r = 0; r < 4; r++) { cR[v][r] = 0.f; cZ[v][r] = 0.f; cNi[v][r] = 0.f; cNh[v][r] = 0.f; }

        #pragma unroll
        for (int v = 0; v < 4; v++) {
            cR[v]  = mfma16(g0h[0], B1[0][v][0], cR[v]);
            cZ[v]  = mfma16(g0h[0], B1[1][v][0], cZ[v]);
            cNi[v] = mfma16(g0h[0], B1[2][v][0], cNi[v]);
            cR[v]  = mfma16(g1h[0], B1[0][v][2], cR[v]);
            cZ[v]  = mfma16(g1h[0], B1[1][v][2], cZ[v]);
            cNh[v] = mfma16(g1h[0], B1[2][v][2], cNh[v]);
            cR[v]  = mfma16(g0h[1], B1[0][v][1], cR[v]);
            cZ[v]  = mfma16(g0h[1], B1[1][v][1], cZ[v]);
            cNi[v] = mfma16(g0h[1], B1[2][v][1], cNi[v]);
            cR[v]  = mfma16(g1h[1], B1[0][v][3], cR[v]);
            cZ[v]  = mfma16(g1h[1], B1[1][v][3], cZ[v]);
            cNh[v] = mfma16(g1h[1], B1[2][v][3], cNh[v]);
            cR[v]  = mfma16(g0l[0], B1[0][v][0], cR[v]);
            cZ[v]  = mfma16(g0l[0], B1[1][v][0], cZ[v]);
            cNi[v] = mfma16(g0l[0], B1[2][v][0], cNi[v]);
            cR[v]  = mfma16(g1l[0], B1[0][v][2], cR[v]);
            cZ[v]  = mfma16(g1l[0], B1[1][v][2], cZ[v]);
            cNh[v] = mfma16(g1l[0], B1[2][v][2], cNh[v]);
            cR[v]  = mfma16(g0l[1], B1[0][v][1], cR[v]);
            cZ[v]  = mfma16(g0l[1], B1[1][v][1], cZ[v]);
            cNi[v] = mfma16(g0l[1], B1[2][v][1], cNi[v]);
            cR[v]  = mfma16(g1l[1], B1[0][v][3], cR[v]);
            cZ[v]  = mfma16(g1l[1], B1[1][v][3], cZ[v]);
            cNh[v] = mfma16(g1l[1], B1[2][v][3], cNh[v]);
        }

        _Float16 w1hi[4], w1lo[4];
        #pragma unroll
        for (int v = 0; v < 4; v++) {
            const float rg = sigm(cR[v][0] + br1[v]);
            const float zg = sigm(cZ[v][0] + bz1[v]);
            const float ng = tanh_fast(cNi[v][0] + bin1[v]
                                       + rg * (cNh[v][0] + bhn1[v]));
            const float h = ng + zg * (h1p[v] - ng);
            h1p[v] = h;
            w1hi[v] = (_Float16)h;
            w1lo[v] = (_Float16)(h - (float)w1hi[v]);
        }
        #pragma unroll
        for (int v = 0; v < 4; v++) {
            h1hi[wb + 16 * v] = w1hi[v];
            h1lo[wb + 16 * v] = w1lo[v];
        }

        xv = xn_;
    }

    // ======== FC epilogue: out[row q] = sum_u fc_w[u] h1[q][u] + fc_b ========
    float s = 0.f;
    #pragma unroll
    for (int v = 0; v < 4; v++) s = fmaf(fc_w[16 * v + n], h1p[v], s);
    s += __shfl_xor(s, 1, 64);
    s += __shfl_xor(s, 2, 64);
    s += __shfl_xor(s, 4, 64);
    s += __shfl_xor(s, 8, 64);     // reduce over 16 n-lanes within q-group
    if (n == 0) out[rowbase + q] = s + fc_b[0];
}

extern "C" void kernel_launch(void* const* d_in, const int* in_sizes, int n_in,
                              void* d_out, int out_size, void* d_ws, size_t ws_size,
                              hipStream_t stream)
{
    const float* x     = (const float*)d_in[0];
    const float* w_ih0 = (const float*)d_in[1];
    const float* w_hh0 = (const float*)d_in[2];
    const float* b_ih0 = (const float*)d_in[3];
    const float* b_hh0 = (const float*)d_in[4];
    const float* w_ih1 = (const float*)d_in[5];
    const float* w_hh1 = (const float*)d_in[6];
    const float* b_ih1 = (const float*)d_in[7];
    const float* b_hh1 = (const float*)d_in[8];
    const float* fc_w  = (const float*)d_in[9];
    const float* fc_b  = (const float*)d_in[10];
    float* out = (float*)d_out;

    hipLaunchKernelGGL(gru_wave, dim3(256), dim3(256), 0, stream,
                       x, w_ih0, w_hh0, b_ih0, b_hh0,
                       w_ih1, w_hh1, b_ih1, b_hh1, fc_w, fc_b, out);
}

// Round 8
// 614.565 us; speedup vs baseline: 2.1075x; 2.1075x over previous
//
#include <hip/hip_runtime.h>

// GRUModel: 2-layer GRU (H=64), B=4096, T=512, fp32 in/out — MFMA round 8.
//
// R8 = R6 (layer-pipelined wave specialization, best @691us) with BOTH MFMA
// operands single fp16 (A-side lo product dropped):
//   - L1 wave: 12 MFMA (was 24); L0 wave: 6 (was 12)
//   - A-frag reads halve (one fp16 plane per layer/parity), packs = 1 cvt
//   - absmax expected ~1e-3 (W systematic 2^-11 + A per-step noise 2^-12);
//     fallback if >1.59e-3: restore A-lo split.
//
// Structure: 256 blocks x 512 threads (8 waves). Waves 0-3 compute layer 0
// at window k; waves 4-7 compute layer 1 at step k-1. One barrier per window
// (anti-dependence only — all reads are satisfied at window start; the
// barrier separates this window's writes from last window's readers).
// h-state fp32 in registers (never quantized in place).
//
// Pipeline hazards (parity = step & 1): every same-parity writer/reader pair
// is separated by exactly one barrier — verified case-by-case in R6.
//
// Frag layouts (m89/m120-verified):
//   A: lane holds A[m=lane&15][k=(lane>>4)*8+j], j=0..7
//   B: lane holds B[k=(lane>>4)*8+j][n=lane&15]
//   C/D: lane holds D[m=(lane>>4)*4+reg][n=lane&15]

typedef _Float16 half8 __attribute__((ext_vector_type(8)));
typedef float    v4f   __attribute__((ext_vector_type(4)));

#define T_LEN 512
#define KS 72   // fp16 row stride of h planes (16B-aligned b128 reads, 8/bank)

static __device__ __forceinline__ float sigm(float x) {
    return 1.0f / (1.0f + __expf(-x));
}
static __device__ __forceinline__ float tanh_fast(float x) {
    return 2.0f / (1.0f + __expf(-2.0f * x)) - 1.0f;
}
static __device__ __forceinline__ v4f mfma16(half8 a, half8 b, v4f c) {
    return __builtin_amdgcn_mfma_f32_16x16x32_f16(a, b, c, 0, 0, 0);
}
static __device__ __forceinline__ half8 ld8(const _Float16* p) {
    return *(const half8*)p;
}

__global__ __launch_bounds__(512, 1)
void gru_mfma(const float* __restrict__ x,
              const float* __restrict__ w_ih0, const float* __restrict__ w_hh0,
              const float* __restrict__ b_ih0, const float* __restrict__ b_hh0,
              const float* __restrict__ w_ih1, const float* __restrict__ w_hh1,
              const float* __restrict__ b_ih1, const float* __restrict__ b_hh1,
              const float* __restrict__ fc_w,  const float* __restrict__ fc_b,
              float* __restrict__ out)
{
    __shared__ __align__(16) float xs[T_LEN * 16];        // [t][m], 32 KB
    __shared__ __align__(16) _Float16 h0f[2][16 * KS];    // h0 fp16, 2 parities
    __shared__ __align__(16) _Float16 h1f[2][16 * KS];    // h1 fp16, 2 parities
    __shared__ float red[64];

    const int tid  = threadIdx.x;
    const int wv   = tid >> 6;
    const int grp  = wv >> 2;       // 0 = layer-0 group, 1 = layer-1 group
    const int w    = wv & 3;        // N-split within group
    const int lane = tid & 63;
    const int n    = lane & 15;
    const int q    = lane >> 4;
    const int u    = w * 16 + n;    // unit owned in gate phase

    // ---- stage this block's 16 x-rows into LDS as [t][m] (coalesced) ----
    const float* xg = x + (size_t)(blockIdx.x * 16) * T_LEN;
    for (int i = tid; i < 16 * T_LEN; i += 512) {
        const int row = i >> 9, t = i & 511;
        xs[t * 16 + row] = xg[row * T_LEN + t];
    }
    // zero parity-1 buffers (read before first write)
    for (int i = tid; i < 16 * KS; i += 512) {
        h0f[1][i] = (_Float16)0;
        h1f[1][i] = (_Float16)0;
    }

    // ---- loop-invariant weight B-fragments (single fp16), group-specific ----
    // grp0 uses c=0,1 (W_hh0, K=64); grp1 uses c=0..3 ([W_ih1 | W_hh1], K=128)
    half8 B[3][4];
    {
        const int rows[3] = {u, 64 + u, 128 + u};
        const float* bc[4];
        if (grp == 0) {
            bc[0] = w_hh0;      bc[1] = w_hh0 + 32;
            bc[2] = w_hh0;      bc[3] = w_hh0 + 32;   // unused dups
        } else {
            bc[0] = w_ih1;      bc[1] = w_ih1 + 32;
            bc[2] = w_hh1;      bc[3] = w_hh1 + 32;
        }
        #pragma unroll
        for (int g = 0; g < 3; g++)
            #pragma unroll
            for (int c = 0; c < 4; c++) {
                const float* r0 = bc[c] + rows[g] * 64 + 8 * q;
                #pragma unroll
                for (int j = 0; j < 8; j++) B[g][c][j] = (_Float16)r0[j];
            }
    }

    // per-lane gate constants for unit u (group-specific)
    float wir = 0.f, wiz = 0.f, win = 0.f, brc = 0.f, bzc = 0.f, binc = 0.f, bhnc = 0.f;
    if (grp == 0) {
        wir = w_ih0[u]; wiz = w_ih0[64 + u]; win = w_ih0[128 + u];
        brc = b_ih0[u] + b_hh0[u];
        bzc = b_ih0[64 + u] + b_hh0[64 + u];
        binc = b_ih0[128 + u]; bhnc = b_hh0[128 + u];
    } else {
        brc = b_ih1[u] + b_hh1[u];
        bzc = b_ih1[64 + u] + b_hh1[64 + u];
        binc = b_ih1[128 + u]; bhnc = b_hh1[128 + u];
    }

    float hst[4] = {0.f, 0.f, 0.f, 0.f};   // fp32 h[m=4q+reg][u] (own layer)

    __syncthreads();

    const int abase = n * KS + 8 * q;       // A-frag base (fp16 elems)

    #pragma unroll 1
    for (int k = 0; k < T_LEN + 1; k++) {
        if (grp == 0) {
            if (k < T_LEN) {
                const int pw = k & 1, pr = pw ^ 1;
                // A-frags of h0(k-1) — written @k-1 pre-barrier, visible now
                const half8 a0 = ld8(&h0f[pr][abase]);
                const half8 a1 = ld8(&h0f[pr][abase + 32]);
                const v4f xv = *(const v4f*)(xs + k * 16 + 4 * q);  // broadcast

                v4f accR, accZ, accN;
                #pragma unroll
                for (int r = 0; r < 4; r++) {
                    accR[r] = fmaf(xv[r], wir, brc);
                    accZ[r] = fmaf(xv[r], wiz, bzc);
                    accN[r] = 0.f;
                }
                accR = mfma16(a0, B[0][0], accR);
                accZ = mfma16(a0, B[1][0], accZ);
                accN = mfma16(a0, B[2][0], accN);
                accR = mfma16(a1, B[0][1], accR);
                accZ = mfma16(a1, B[1][1], accZ);
                accN = mfma16(a1, B[2][1], accN);

                #pragma unroll
                for (int r = 0; r < 4; r++) {
                    const float rg = sigm(accR[r]);
                    const float zg = sigm(accZ[r]);
                    const float inn = fmaf(xv[r], win, binc);
                    const float ng = tanh_fast(inn + rg * (accN[r] + bhnc));
                    const float h = ng + zg * (hst[r] - ng);
                    hst[r] = h;
                    h0f[pw][(4 * q + r) * KS + u] = (_Float16)h;
                }
            }
        } else {
            if (k > 0) {
                const int t = k - 1;
                const int pw = t & 1;       // h0(t) parity; h1(t) write parity
                const int p1 = pw ^ 1;      // h1(t-1) parity
                const half8 g00 = ld8(&h0f[pw][abase]);        // h0new(t)
                const half8 g01 = ld8(&h0f[pw][abase + 32]);
                const half8 g10 = ld8(&h1f[p1][abase]);        // h1(t-1)
                const half8 g11 = ld8(&h1f[p1][abase + 32]);

                v4f aR, aZ, aNi, aNh;
                #pragma unroll
                for (int r = 0; r < 4; r++) {
                    aR[r] = brc;  aZ[r] = bzc;  aNi[r] = binc;  aNh[r] = bhnc;
                }
                // r,z fold i-side and h-side into one acc; n keeps them apart
                aR  = mfma16(g00, B[0][0], aR);
                aZ  = mfma16(g00, B[1][0], aZ);
                aNi = mfma16(g00, B[2][0], aNi);
                aNh = mfma16(g10, B[2][2], aNh);
                aR  = mfma16(g01, B[0][1], aR);
                aZ  = mfma16(g01, B[1][1], aZ);
                aNi = mfma16(g01, B[2][1], aNi);
                aNh = mfma16(g11, B[2][3], aNh);
                aR  = mfma16(g10, B[0][2], aR);
                aZ  = mfma16(g10, B[1][2], aZ);
                aR  = mfma16(g11, B[0][3], aR);
                aZ  = mfma16(g11, B[1][3], aZ);

                #pragma unroll
                for (int r = 0; r < 4; r++) {
                    const float rg = sigm(aR[r]);
                    const float zg = sigm(aZ[r]);
                    const float ng = tanh_fast(aNi[r] + rg * aNh[r]);
                    const float h = ng + zg * (hst[r] - ng);
                    hst[r] = h;
                    h1f[pw][(4 * q + r) * KS + u] = (_Float16)h;
                }
            }
        }
        __syncthreads();   // the ONE barrier per window (anti-dependence)
    }

    // ======== FC epilogue: out[m] = sum_u fc_w[u] h1[m][u] + fc_b ========
    if (grp == 1) {
        const float fw = fc_w[u];
        #pragma unroll
        for (int r = 0; r < 4; r++) {
            float v = fw * hst[r];
            v += __shfl_xor(v, 1, 64);
            v += __shfl_xor(v, 2, 64);
            v += __shfl_xor(v, 4, 64);
            v += __shfl_xor(v, 8, 64);   // sum over 16 n-lanes (q preserved)
            if (n == 0) red[(4 * q + r) * 4 + w] = v;
        }
    }
    __syncthreads();
    if (tid < 16) {
        const float s = red[tid * 4] + red[tid * 4 + 1] + red[tid * 4 + 2] + red[tid * 4 + 3];
        out[blockIdx.x * 16 + tid] = s + fc_b[0];
    }
}

extern "C" void kernel_launch(void* const* d_in, const int* in_sizes, int n_in,
                              void* d_out, int out_size, void* d_ws, size_t ws_size,
                              hipStream_t stream)
{
    const float* x     = (const float*)d_in[0];
    const float* w_ih0 = (const float*)d_in[1];
    const float* w_hh0 = (const float*)d_in[2];
    const float* b_ih0 = (const float*)d_in[3];
    const float* b_hh0 = (const float*)d_in[4];
    const float* w_ih1 = (const float*)d_in[5];
    const float* w_hh1 = (const float*)d_in[6];
    const float* b_ih1 = (const float*)d_in[7];
    const float* b_hh1 = (const float*)d_in[8];
    const float* fc_w  = (const float*)d_in[9];
    const float* fc_b  = (const float*)d_in[10];
    float* out = (float*)d_out;

    hipLaunchKernelGGL(gru_mfma, dim3(256), dim3(512), 0, stream,
                       x, w_ih0, w_hh0, b_ih0, b_hh0,
                       w_ih1, w_hh1, b_ih1, b_hh1, fc_w, fc_b, out);
}